// Round 7
// baseline (212.638 us; speedup 1.0000x reference)
//
#include <hip/hip_runtime.h>
#include <math.h>

typedef unsigned short u16;
typedef __attribute__((ext_vector_type(8))) _Float16 half8;    // 8 fp16
typedef __attribute__((ext_vector_type(4))) float    f32x4;

#define BATCH 4
#define NPB   4096      // pixels per batch (H*W)
#define BN    16384     // BATCH * NPB
#define CC    256       // input channels
#define D     128       // output channels (C/2)
#define LOG2E 1.44269504088896f
#define THR   8.0f      // deferred-rescale threshold (exp2 domain; P <= 256 in fp16)

#if __has_builtin(__builtin_amdgcn_exp2f)
#define EXP2(x) __builtin_amdgcn_exp2f(x)
#else
#define EXP2(x) exp2f(x)
#endif

// 16-lane (DPP row) reductions on the VALU pipe — no LDS crossbar.
template<int CTRL>
__device__ __forceinline__ float dpp_mov(float x) {
    return __builtin_bit_cast(float, __builtin_amdgcn_update_dpp(
        __builtin_bit_cast(int, x), __builtin_bit_cast(int, x),
        CTRL, 0xf, 0xf, false));
}
__device__ __forceinline__ float dpp_row_max(float x) {
    x = fmaxf(x, dpp_mov<0x128>(x));   // row_ror:8
    x = fmaxf(x, dpp_mov<0x124>(x));   // row_ror:4
    x = fmaxf(x, dpp_mov<0x122>(x));   // row_ror:2
    x = fmaxf(x, dpp_mov<0x121>(x));   // row_ror:1
    return x;
}
__device__ __forceinline__ float dpp_row_sum(float x) {
    x += dpp_mov<0x128>(x);
    x += dpp_mov<0x124>(x);
    x += dpp_mov<0x122>(x);
    x += dpp_mov<0x121>(x);
    return x;
}

// ---------------------------------------------------------------------------
// Prep: W[mat] (f32 [256][128]) -> Wt[mat][c][k] fp16 (c-major, contiguous k).
// mat 0 (K) pre-scaled by log2e. 128 blocks x 256 threads x 4 elements.
// ---------------------------------------------------------------------------
__global__ __launch_bounds__(256) void prep_kernel(
    const float* __restrict__ Wk, const float* __restrict__ Wq,
    const float* __restrict__ Wv, const float* __restrict__ Ws,
    u16* __restrict__ Wt)
{
    const int f   = (blockIdx.x * 256 + threadIdx.x) * 4;   // flat output idx
    const int mat = f >> 15;
    const int rem = f & 32767;
    const int c   = rem >> 8;
    const int k0  = rem & 255;
    const float* W = (mat == 0) ? Wk : (mat == 1) ? Wq : (mat == 2) ? Wv : Ws;
    const float scale = (mat == 0) ? LOG2E : 1.0f;
    _Float16 t4[4];
#pragma unroll
    for (int i = 0; i < 4; ++i)
        t4[i] = (_Float16)(W[(size_t)(k0 + i) * D + c] * scale);
    *(uint2*)&Wt[(size_t)mat * 32768 + (size_t)c * 256 + k0] = *(const uint2*)t4;
}

// ---------------------------------------------------------------------------
// Projection: grid (128, 4) = 128-pixel x-tile x one matrix per block.
// Emits MFMA-fragment-ordered Qf/Vf so attn reads each fragment as one
// contiguous, coalesced 1 KB global load (verified in v7).
//   Qf: (m,k) at ((m>>4)*4 + (k>>5))*512 + ((k>>3)&3)*128 + (m&15)*8 + (k&7)
//   Vf (per batch): (c,m) at ((m>>5)*8 + (c>>4))*512 + (c&15)*32 + (m&31)
// ---------------------------------------------------------------------------
#define APJ 264         // As row pitch in u16 (528 B: 16B-aligned, 4-bank row shift)

__global__ __launch_bounds__(256, 2) void proj_kernel(
    const float* __restrict__ x, const u16* __restrict__ Wt,
    const float* __restrict__ bk, const float* __restrict__ bq,
    const float* __restrict__ bv, const float* __restrict__ bs,
    u16* __restrict__ Kh, u16* __restrict__ Qf,
    u16* __restrict__ Vf, float* __restrict__ Sc)
{
    __shared__ __align__(16) u16 As[128][APJ];   // 66 KB -> 2 blocks/CU

    const int tid = threadIdx.x;
    const int wv  = tid >> 6;
    const int l   = tid & 63;
    const int l15 = l & 15;
    const int l4  = l >> 4;
    const int by  = blockIdx.y;
    const int gm0 = blockIdx.x * 128;
    const int c0  = wv * 32;

    // ---- W fragments from Wt: wf[ct][kc], lane -> W[k=kc*32+l4*8..+8][c0+ct*16+l15]
    const u16* wb = Wt + (size_t)by * 32768 + (size_t)(c0 + l15) * 256 + l4 * 8;
    half8 wf[2][8];
#pragma unroll
    for (int ct = 0; ct < 2; ++ct)
#pragma unroll
        for (int kc = 0; kc < 8; ++kc)
            wf[ct][kc] = *(const half8*)(wb + ct * 16 * 256 + kc * 32);

    // ---- stage the 128x256 x-tile once (coalesced: thread t -> float4 i*256+t)
    {
        const float4* xg = (const float4*)(x + (size_t)gm0 * CC);
#pragma unroll 8
        for (int i = 0; i < 32; ++i) {
            const int f = i * 256 + tid;           // flat float4 index
            const float4 v = xg[f];
            const int row = f >> 6, col4 = f & 63;
            _Float16 h[4] = {(_Float16)v.x, (_Float16)v.y,
                             (_Float16)v.z, (_Float16)v.w};
            *(uint2*)&As[row][col4 * 4] = *(const uint2*)h;
        }
    }
    __syncthreads();

    f32x4 acc[8][2];
#pragma unroll
    for (int mt = 0; mt < 8; ++mt) {
        acc[mt][0] = (f32x4){0.f, 0.f, 0.f, 0.f};
        acc[mt][1] = (f32x4){0.f, 0.f, 0.f, 0.f};
    }

    if (by == 2) {
        for (int kc = 0; kc < 8; ++kc)
#pragma unroll
            for (int mt = 0; mt < 8; ++mt) {
                const half8 a = *(const half8*)&As[mt * 16 + l15][kc * 32 + l4 * 8];
                acc[mt][0] = __builtin_amdgcn_mfma_f32_16x16x32_f16(a, wf[0][kc], acc[mt][0], 0, 0, 0);
                acc[mt][1] = __builtin_amdgcn_mfma_f32_16x16x32_f16(a, wf[1][kc], acc[mt][1], 0, 0, 0);
            }
        // V: lane holds D[m = (gm0&4095)+l4*4+r + mt*16][c = c0+ct*16+l15].
        const float bb[2] = {bv[c0 + l15], bv[c0 + 16 + l15]};
        const int batch = gm0 >> 12;
        const int mb    = (gm0 & 4095) >> 5;      // 32-m block base (local)
        u16* vbp = Vf + (size_t)batch * (D * NPB);
#pragma unroll
        for (int mt = 0; mt < 8; ++mt)
#pragma unroll
            for (int ct = 0; ct < 2; ++ct) {
                _Float16 t4[4];
#pragma unroll
                for (int r = 0; r < 4; ++r)
                    t4[r] = (_Float16)(acc[mt][ct][r] + bb[ct]);
                const int blk = (mb + (mt >> 1)) * 8 + wv * 2 + ct;
                const int off = blk * 512 + l15 * 32 + (mt & 1) * 16 + l4 * 4;
                *(uint2*)&vbp[off] = *(const uint2*)t4;
            }
    } else {
        for (int kc = 0; kc < 8; ++kc)
#pragma unroll
            for (int mt = 0; mt < 8; ++mt) {
                const half8 a = *(const half8*)&As[mt * 16 + l15][kc * 32 + l4 * 8];
                acc[mt][0] = __builtin_amdgcn_mfma_f32_16x16x32_f16(wf[0][kc], a, acc[mt][0], 0, 0, 0);
                acc[mt][1] = __builtin_amdgcn_mfma_f32_16x16x32_f16(wf[1][kc], a, acc[mt][1], 0, 0, 0);
            }
        // swapped: D[c][m] — lane holds c = c0+ct*16+l4*4+r, m = gm0+mt*16+l15
        if (by == 3) {
            float bb2[2][4];
#pragma unroll
            for (int ct = 0; ct < 2; ++ct)
#pragma unroll
                for (int r = 0; r < 4; ++r)
                    bb2[ct][r] = bs[c0 + ct * 16 + l4 * 4 + r];
#pragma unroll
            for (int mt = 0; mt < 8; ++mt) {
                const int m = gm0 + mt * 16 + l15;
#pragma unroll
                for (int ct = 0; ct < 2; ++ct) {
                    float4 v;
                    v.x = acc[mt][ct][0] + bb2[ct][0];
                    v.y = acc[mt][ct][1] + bb2[ct][1];
                    v.z = acc[mt][ct][2] + bb2[ct][2];
                    v.w = acc[mt][ct][3] + bb2[ct][3];
                    *(float4*)&Sc[(size_t)m * D + c0 + ct * 16 + l4 * 4] = v;
                }
            }
        } else if (by == 1) {
            // Q -> fragment layout Qf (indexed by GLOBAL m)
            float bb2[2][4];
#pragma unroll
            for (int ct = 0; ct < 2; ++ct)
#pragma unroll
                for (int r = 0; r < 4; ++r)
                    bb2[ct][r] = bq[c0 + ct * 16 + l4 * 4 + r];
#pragma unroll
            for (int mt = 0; mt < 8; ++mt) {
                const int blk = (((gm0 >> 4) + mt) << 2) + wv;
#pragma unroll
                for (int ct = 0; ct < 2; ++ct) {
                    _Float16 t4[4];
#pragma unroll
                    for (int r = 0; r < 4; ++r)
                        t4[r] = (_Float16)(acc[mt][ct][r] + bb2[ct][r]);
                    const int off = blk * 512 + (ct * 2 + (l4 >> 1)) * 128
                                    + l15 * 8 + (l4 & 1) * 4;
                    *(uint2*)&Qf[off] = *(const uint2*)t4;
                }
            }
        } else {
            // K -> row-major [m][c] (read once per block by attn), log2e-scaled
            float bb2[2][4];
#pragma unroll
            for (int ct = 0; ct < 2; ++ct)
#pragma unroll
                for (int r = 0; r < 4; ++r)
                    bb2[ct][r] = bk[c0 + ct * 16 + l4 * 4 + r] * LOG2E;
#pragma unroll
            for (int mt = 0; mt < 8; ++mt) {
                const int m = gm0 + mt * 16 + l15;
#pragma unroll
                for (int ct = 0; ct < 2; ++ct) {
                    _Float16 t4[4];
#pragma unroll
                    for (int r = 0; r < 4; ++r)
                        t4[r] = (_Float16)(acc[mt][ct][r] + bb2[ct][r]);
                    *(uint2*)&Kh[(size_t)m * D + c0 + ct * 16 + l4 * 4] =
                        *(const uint2*)t4;
                }
            }
        }
    }
}

// ---------------------------------------------------------------------------
// Flash attention v8 = v7 (fragment-layout register reads, no main-loop LDS
// staging / barriers) + deferred rescale (THR=8, proven in v2/v4) + 2-slot
// two-stage merge (LDS 78.8 -> 45.1 KB -> 3 blocks/CU = 3 waves/SIMD).
// 512 blocks x 32 n-rows; 4 waves = 4 disjoint m-quarters (32 iters x 32 m).
// ---------------------------------------------------------------------------
#define VPP 40          // Ps row pitch (u16)
#define OBP 132         // Obuf row pitch (f32): 528 B, 16B-aligned

__global__ __launch_bounds__(256, 3) void attn_kernel(
    const u16* __restrict__ Kh, const u16* __restrict__ Qf,
    const u16* __restrict__ Vf, const float* __restrict__ Sc,
    float* __restrict__ out)
{
    __shared__ __align__(16) u16   Ps[4][2][16][VPP];   // 10 KB
    __shared__ __align__(16) float Obuf[2][32][OBP];    // 33.8 KB merge slots
    __shared__ float ml[4][2][32];                      // 1 KB
    // total 45.1 KB -> 3 blocks/CU

    const int tid = threadIdx.x;
    const int wv  = tid >> 6;          // m-quarter
    const int l   = tid & 63;
    const int l15 = l & 15;
    const int l4  = l >> 4;

    // XCD-affinity remap: each XCD pair serves one batch (K+Qf+Vf ~3 MB / L2)
    const int bx    = blockIdx.x;
    const int xcd   = bx & 7;
    const int batch = xcd >> 1;
    const int tile  = ((xcd & 1) << 6) | (bx >> 3);
    const int gr0   = batch * NPB + tile * 32;      // block's 32 K-rows (out rows)

    // ---- K A-frags (proven 16x16x32 mapping), held in registers all loop
    half8 kf[2][4];
#pragma unroll
    for (int nt = 0; nt < 2; ++nt)
#pragma unroll
        for (int kc = 0; kc < 4; ++kc)
            kf[nt][kc] = *(const half8*)(
                Kh + (size_t)(gr0 + nt * 16 + l15) * D + kc * 32 + l4 * 8);

    // ---- fragment-layout bases
    const int  qtb = (batch * NPB + wv * 1024) >> 4;   // Q 16-m tile base (global m)
    const int  vbb = wv * 32;                          // V 32-m block base (local m)
    const u16* vb  = Vf + (size_t)batch * (D * NPB);
    const int  vl  = l15 * 4 + l4;                     // V lane permutation

    f32x4 Oc[2][8];
#pragma unroll
    for (int nt = 0; nt < 2; ++nt)
#pragma unroll
        for (int ct = 0; ct < 8; ++ct)
            Oc[nt][ct] = (f32x4){0.f, 0.f, 0.f, 0.f};
    float mold[2][4], lsum[2][4];
#pragma unroll
    for (int nt = 0; nt < 2; ++nt)
#pragma unroll
        for (int r = 0; r < 4; ++r) { mold[nt][r] = -1e30f; lsum[nt][r] = 0.f; }

    for (int it = 0; it < 32; ++it) {
        // ---- all fragment loads up front (contiguous 1 KB per instruction)
        half8 qf[2][4];
#pragma unroll
        for (int mt = 0; mt < 2; ++mt)
#pragma unroll
            for (int kc = 0; kc < 4; ++kc)
                qf[mt][kc] = *(const half8*)(
                    Qf + (size_t)(((qtb + it * 2 + mt) << 2) + kc) * 512 + l * 8);
        half8 vf[8];
#pragma unroll
        for (int ct = 0; ct < 8; ++ct)
            vf[ct] = *(const half8*)(
                vb + (size_t)(((vbb + it) << 3) + ct) * 512 + vl * 8);

        // ---- S' = (K*log2e) @ Q^T : 32n x 32m, exp2 domain (proven path)
        f32x4 sacc[2][2];
        sacc[0][0] = (f32x4){0.f, 0.f, 0.f, 0.f};
        sacc[0][1] = (f32x4){0.f, 0.f, 0.f, 0.f};
        sacc[1][0] = (f32x4){0.f, 0.f, 0.f, 0.f};
        sacc[1][1] = (f32x4){0.f, 0.f, 0.f, 0.f};
        __builtin_amdgcn_s_setprio(1);
#pragma unroll
        for (int kc = 0; kc < 4; ++kc)
#pragma unroll
            for (int nt = 0; nt < 2; ++nt)
#pragma unroll
                for (int mt = 0; mt < 2; ++mt)
                    sacc[nt][mt] = __builtin_amdgcn_mfma_f32_16x16x32_f16(
                        kf[nt][kc], qf[mt][kc], sacc[nt][mt], 0, 0, 0);
        __builtin_amdgcn_s_setprio(0);

        // ---- online softmax with deferred rescale (T13, THR=8)
        float rmax[2][4];
        int grow = 0;
#pragma unroll
        for (int nt = 0; nt < 2; ++nt)
#pragma unroll
            for (int r = 0; r < 4; ++r) {
                rmax[nt][r] = dpp_row_max(fmaxf(sacc[nt][0][r], sacc[nt][1][r]));
                grow |= (rmax[nt][r] > mold[nt][r] + THR) ? 1 : 0;
            }
        if (__any(grow)) {
#pragma unroll
            for (int nt = 0; nt < 2; ++nt)
#pragma unroll
                for (int r = 0; r < 4; ++r) {
                    const float mnew  = fmaxf(mold[nt][r], rmax[nt][r]);
                    const float alpha = EXP2(mold[nt][r] - mnew);
                    mold[nt][r] = mnew;
                    lsum[nt][r] *= alpha;
#pragma unroll
                    for (int ct = 0; ct < 8; ++ct) Oc[nt][ct][r] *= alpha;
                }
        }
#pragma unroll
        for (int nt = 0; nt < 2; ++nt)
#pragma unroll
            for (int r = 0; r < 4; ++r) {
                const float p0 = EXP2(sacc[nt][0][r] - mold[nt][r]);
                const float p1 = EXP2(sacc[nt][1][r] - mold[nt][r]);
                lsum[nt][r] += p0 + p1;
                Ps[wv][nt][l4 * 4 + r][l15]      = __builtin_bit_cast(u16, (_Float16)p0);
                Ps[wv][nt][l4 * 4 + r][16 + l15] = __builtin_bit_cast(u16, (_Float16)p1);
            }
        asm volatile("s_waitcnt lgkmcnt(0)" ::: "memory");   // wave-private Ps

        // ---- PV: O += P @ V (proven path)
        __builtin_amdgcn_s_setprio(1);
#pragma unroll
        for (int nt = 0; nt < 2; ++nt) {
            const half8 pf = *(const half8*)&Ps[wv][nt][l15][l4 * 8];
#pragma unroll
            for (int ct = 0; ct < 8; ++ct)
                Oc[nt][ct] = __builtin_amdgcn_mfma_f32_16x16x32_f16(
                    pf, vf[ct], Oc[nt][ct], 0, 0, 0);
        }
        __builtin_amdgcn_s_setprio(0);
    }

    // ---- full per-row sums across the 16 m-lanes (once, DPP)
#pragma unroll
    for (int nt = 0; nt < 2; ++nt)
#pragma unroll
        for (int r = 0; r < 4; ++r)
            lsum[nt][r] = dpp_row_sum(lsum[nt][r]);

    // ---- publish per-wave (m, l) per row
    if (l15 == 0) {
#pragma unroll
        for (int nt = 0; nt < 2; ++nt)
#pragma unroll
            for (int r = 0; r < 4; ++r) {
                ml[wv][0][nt * 16 + l4 * 4 + r] = mold[nt][r];
                ml[wv][1][nt * 16 + l4 * 4 + r] = lsum[nt][r];
            }
    }
    __syncthreads();

    // ---- scale factors into common max-frame
    float fw[2][4];
#pragma unroll
    for (int nt = 0; nt < 2; ++nt)
#pragma unroll
        for (int r = 0; r < 4; ++r) {
            const int row = nt * 16 + l4 * 4 + r;
            const float M = fmaxf(fmaxf(ml[0][0][row], ml[1][0][row]),
                                  fmaxf(ml[2][0][row], ml[3][0][row]));
            fw[nt][r] = EXP2(mold[nt][r] - M);
        }

    // ---- two-stage 4->2->1 additive merge (2 LDS slots)
    if (wv >= 2) {
#pragma unroll
        for (int nt = 0; nt < 2; ++nt)
#pragma unroll
            for (int r = 0; r < 4; ++r) {
                const int row = nt * 16 + l4 * 4 + r;
#pragma unroll
                for (int ct = 0; ct < 8; ++ct)
                    Obuf[wv - 2][row][ct * 16 + l15] = Oc[nt][ct][r] * fw[nt][r];
            }
    }
    __syncthreads();
    if (wv < 2) {
#pragma unroll
        for (int nt = 0; nt < 2; ++nt)
#pragma unroll
            for (int r = 0; r < 4; ++r) {
                const int row = nt * 16 + l4 * 4 + r;
#pragma unroll
                for (int ct = 0; ct < 8; ++ct)
                    Obuf[wv][row][ct * 16 + l15] += Oc[nt][ct][r] * fw[nt][r];
            }
    }
    __syncthreads();

    // ---- final: thread -> (row = wv*8 + l/8, 16 c per lane-octet)
    {
        const int row = wv * 8 + (l >> 3);
        const int cb  = (l & 7) * 16;
        const float M = fmaxf(fmaxf(ml[0][0][row], ml[1][0][row]),
                              fmaxf(ml[2][0][row], ml[3][0][row]));
        float L = 0.f;
#pragma unroll
        for (int s = 0; s < 4; ++s)
            L += ml[s][1][row] * EXP2(ml[s][0][row] - M);
        const float invL = 1.f / L;
        const size_t grow_ = (size_t)(gr0 + row);
#pragma unroll
        for (int j = 0; j < 4; ++j) {
            const int c = cb + j * 4;
            const f32x4 a = *(const f32x4*)&Obuf[0][row][c];
            const f32x4 b = *(const f32x4*)&Obuf[1][row][c];
            const float4 sc = *(const float4*)&Sc[grow_ * D + c];
            float4 o;
            o.x = (a[0] + b[0]) * invL + sc.x;
            o.y = (a[1] + b[1]) * invL + sc.y;
            o.z = (a[2] + b[2]) * invL + sc.z;
            o.w = (a[3] + b[3]) * invL + sc.w;
            *(float4*)&out[grow_ * D + c] = o;
        }
    }
}

extern "C" void kernel_launch(void* const* d_in, const int* in_sizes, int n_in,
                              void* d_out, int out_size, void* d_ws, size_t ws_size,
                              hipStream_t stream) {
    const float* x  = (const float*)d_in[0];
    const float* Wk = (const float*)d_in[1];
    const float* bk = (const float*)d_in[2];
    const float* Wq = (const float*)d_in[3];
    const float* bq = (const float*)d_in[4];
    const float* Wv = (const float*)d_in[5];
    const float* bv = (const float*)d_in[6];
    const float* Ws = (const float*)d_in[7];
    const float* bs = (const float*)d_in[8];
    float* out = (float*)d_out;

    u16*   Kh = (u16*)d_ws;                       // 4 MB fp16 [m][c] (log2e-scaled)
    u16*   Qf = Kh + (size_t)BN * D;              // 4 MB fp16, fragment layout
    u16*   Vf = Qf + (size_t)BN * D;              // 4 MB fp16, fragment layout
    float* Sc = (float*)(Vf + (size_t)BN * D);    // 8 MB fp32
    u16*   Wt = (u16*)(Sc + (size_t)BN * D);      // 256 KB fp16 W^T (4 mats)

    prep_kernel<<<128, 256, 0, stream>>>(Wk, Wq, Wv, Ws, Wt);
    proj_kernel<<<dim3(128, 4), 256, 0, stream>>>(x, Wt, bk, bq, bv, bs,
                                                  Kh, Qf, Vf, Sc);
    attn_kernel<<<512, 256, 0, stream>>>(Kh, Qf, Vf, Sc, out);
}

// Round 8
// 155.211 us; speedup vs baseline: 1.3700x; 1.3700x over previous
//
#include <hip/hip_runtime.h>
#include <math.h>

typedef unsigned short u16;
typedef __attribute__((ext_vector_type(8))) _Float16 half8;    // 8 fp16
typedef __attribute__((ext_vector_type(4))) float    f32x4;

#define BATCH 4
#define NPB   4096      // pixels per batch (H*W)
#define BN    16384     // BATCH * NPB
#define CC    256       // input channels
#define D     128       // output channels (C/2)
#define LOG2E 1.44269504088896f
#define THR   8.0f      // deferred-rescale threshold (exp2 domain; P <= 256 in fp16)

#if __has_builtin(__builtin_amdgcn_exp2f)
#define EXP2(x) __builtin_amdgcn_exp2f(x)
#else
#define EXP2(x) exp2f(x)
#endif

// 16-lane (DPP row) reductions on the VALU pipe — no LDS crossbar.
template<int CTRL>
__device__ __forceinline__ float dpp_mov(float x) {
    return __builtin_bit_cast(float, __builtin_amdgcn_update_dpp(
        __builtin_bit_cast(int, x), __builtin_bit_cast(int, x),
        CTRL, 0xf, 0xf, false));
}
__device__ __forceinline__ float dpp_row_max(float x) {
    x = fmaxf(x, dpp_mov<0x128>(x));   // row_ror:8
    x = fmaxf(x, dpp_mov<0x124>(x));   // row_ror:4
    x = fmaxf(x, dpp_mov<0x122>(x));   // row_ror:2
    x = fmaxf(x, dpp_mov<0x121>(x));   // row_ror:1
    return x;
}
__device__ __forceinline__ float dpp_row_sum(float x) {
    x += dpp_mov<0x128>(x);
    x += dpp_mov<0x124>(x);
    x += dpp_mov<0x122>(x);
    x += dpp_mov<0x121>(x);
    return x;
}

// ---------------------------------------------------------------------------
// Prep: W[mat] (f32 [256][128]) -> Wt[mat][c][k] fp16 (c-major, contiguous k).
// mat 0 (K) pre-scaled by log2e. 128 blocks x 256 threads x 4 elements.
// ---------------------------------------------------------------------------
__global__ __launch_bounds__(256) void prep_kernel(
    const float* __restrict__ Wk, const float* __restrict__ Wq,
    const float* __restrict__ Wv, const float* __restrict__ Ws,
    u16* __restrict__ Wt)
{
    const int f   = (blockIdx.x * 256 + threadIdx.x) * 4;   // flat output idx
    const int mat = f >> 15;
    const int rem = f & 32767;
    const int c   = rem >> 8;
    const int k0  = rem & 255;
    const float* W = (mat == 0) ? Wk : (mat == 1) ? Wq : (mat == 2) ? Wv : Ws;
    const float scale = (mat == 0) ? LOG2E : 1.0f;
    _Float16 t4[4];
#pragma unroll
    for (int i = 0; i < 4; ++i)
        t4[i] = (_Float16)(W[(size_t)(k0 + i) * D + c] * scale);
    *(uint2*)&Wt[(size_t)mat * 32768 + (size_t)c * 256 + k0] = *(const uint2*)t4;
}

// ---------------------------------------------------------------------------
// Projection: grid (128, 4) = 128-pixel x-tile x one matrix per block.
// Emits MFMA-fragment-ordered Qf/Vf so attn reads each fragment as one
// contiguous, coalesced 1 KB global load (verified in v7/v8).
//   Qf: (m,k) at ((m>>4)*4 + (k>>5))*512 + ((k>>3)&3)*128 + (m&15)*8 + (k&7)
//   Vf (per batch): (c,m) at ((m>>5)*8 + (c>>4))*512 + (c&15)*32 + (m&31)
// ---------------------------------------------------------------------------
#define APJ 264         // As row pitch in u16 (528 B: 16B-aligned, 4-bank row shift)

__global__ __launch_bounds__(256, 2) void proj_kernel(
    const float* __restrict__ x, const u16* __restrict__ Wt,
    const float* __restrict__ bk, const float* __restrict__ bq,
    const float* __restrict__ bv, const float* __restrict__ bs,
    u16* __restrict__ Kh, u16* __restrict__ Qf,
    u16* __restrict__ Vf, float* __restrict__ Sc)
{
    __shared__ __align__(16) u16 As[128][APJ];   // 66 KB -> 2 blocks/CU

    const int tid = threadIdx.x;
    const int wv  = tid >> 6;
    const int l   = tid & 63;
    const int l15 = l & 15;
    const int l4  = l >> 4;
    const int by  = blockIdx.y;
    const int gm0 = blockIdx.x * 128;
    const int c0  = wv * 32;

    // ---- W fragments from Wt: wf[ct][kc], lane -> W[k=kc*32+l4*8..+8][c0+ct*16+l15]
    const u16* wb = Wt + (size_t)by * 32768 + (size_t)(c0 + l15) * 256 + l4 * 8;
    half8 wf[2][8];
#pragma unroll
    for (int ct = 0; ct < 2; ++ct)
#pragma unroll
        for (int kc = 0; kc < 8; ++kc)
            wf[ct][kc] = *(const half8*)(wb + ct * 16 * 256 + kc * 32);

    // ---- stage the 128x256 x-tile once (coalesced: thread t -> float4 i*256+t)
    {
        const float4* xg = (const float4*)(x + (size_t)gm0 * CC);
#pragma unroll 8
        for (int i = 0; i < 32; ++i) {
            const int f = i * 256 + tid;           // flat float4 index
            const float4 v = xg[f];
            const int row = f >> 6, col4 = f & 63;
            _Float16 h[4] = {(_Float16)v.x, (_Float16)v.y,
                             (_Float16)v.z, (_Float16)v.w};
            *(uint2*)&As[row][col4 * 4] = *(const uint2*)h;
        }
    }
    __syncthreads();

    f32x4 acc[8][2];
#pragma unroll
    for (int mt = 0; mt < 8; ++mt) {
        acc[mt][0] = (f32x4){0.f, 0.f, 0.f, 0.f};
        acc[mt][1] = (f32x4){0.f, 0.f, 0.f, 0.f};
    }

    if (by == 2) {
        for (int kc = 0; kc < 8; ++kc)
#pragma unroll
            for (int mt = 0; mt < 8; ++mt) {
                const half8 a = *(const half8*)&As[mt * 16 + l15][kc * 32 + l4 * 8];
                acc[mt][0] = __builtin_amdgcn_mfma_f32_16x16x32_f16(a, wf[0][kc], acc[mt][0], 0, 0, 0);
                acc[mt][1] = __builtin_amdgcn_mfma_f32_16x16x32_f16(a, wf[1][kc], acc[mt][1], 0, 0, 0);
            }
        // V: lane holds D[m = (gm0&4095)+l4*4+r + mt*16][c = c0+ct*16+l15].
        const float bb[2] = {bv[c0 + l15], bv[c0 + 16 + l15]};
        const int batch = gm0 >> 12;
        const int mb    = (gm0 & 4095) >> 5;      // 32-m block base (local)
        u16* vbp = Vf + (size_t)batch * (D * NPB);
#pragma unroll
        for (int mt = 0; mt < 8; ++mt)
#pragma unroll
            for (int ct = 0; ct < 2; ++ct) {
                _Float16 t4[4];
#pragma unroll
                for (int r = 0; r < 4; ++r)
                    t4[r] = (_Float16)(acc[mt][ct][r] + bb[ct]);
                const int blk = (mb + (mt >> 1)) * 8 + wv * 2 + ct;
                const int off = blk * 512 + l15 * 32 + (mt & 1) * 16 + l4 * 4;
                *(uint2*)&vbp[off] = *(const uint2*)t4;
            }
    } else {
        for (int kc = 0; kc < 8; ++kc)
#pragma unroll
            for (int mt = 0; mt < 8; ++mt) {
                const half8 a = *(const half8*)&As[mt * 16 + l15][kc * 32 + l4 * 8];
                acc[mt][0] = __builtin_amdgcn_mfma_f32_16x16x32_f16(wf[0][kc], a, acc[mt][0], 0, 0, 0);
                acc[mt][1] = __builtin_amdgcn_mfma_f32_16x16x32_f16(wf[1][kc], a, acc[mt][1], 0, 0, 0);
            }
        // swapped: D[c][m] — lane holds c = c0+ct*16+l4*4+r, m = gm0+mt*16+l15
        if (by == 3) {
            float bb2[2][4];
#pragma unroll
            for (int ct = 0; ct < 2; ++ct)
#pragma unroll
                for (int r = 0; r < 4; ++r)
                    bb2[ct][r] = bs[c0 + ct * 16 + l4 * 4 + r];
#pragma unroll
            for (int mt = 0; mt < 8; ++mt) {
                const int m = gm0 + mt * 16 + l15;
#pragma unroll
                for (int ct = 0; ct < 2; ++ct) {
                    float4 v;
                    v.x = acc[mt][ct][0] + bb2[ct][0];
                    v.y = acc[mt][ct][1] + bb2[ct][1];
                    v.z = acc[mt][ct][2] + bb2[ct][2];
                    v.w = acc[mt][ct][3] + bb2[ct][3];
                    *(float4*)&Sc[(size_t)m * D + c0 + ct * 16 + l4 * 4] = v;
                }
            }
        } else if (by == 1) {
            // Q -> fragment layout Qf (indexed by GLOBAL m)
            float bb2[2][4];
#pragma unroll
            for (int ct = 0; ct < 2; ++ct)
#pragma unroll
                for (int r = 0; r < 4; ++r)
                    bb2[ct][r] = bq[c0 + ct * 16 + l4 * 4 + r];
#pragma unroll
            for (int mt = 0; mt < 8; ++mt) {
                const int blk = (((gm0 >> 4) + mt) << 2) + wv;
#pragma unroll
                for (int ct = 0; ct < 2; ++ct) {
                    _Float16 t4[4];
#pragma unroll
                    for (int r = 0; r < 4; ++r)
                        t4[r] = (_Float16)(acc[mt][ct][r] + bb2[ct][r]);
                    const int off = blk * 512 + (ct * 2 + (l4 >> 1)) * 128
                                    + l15 * 8 + (l4 & 1) * 4;
                    *(uint2*)&Qf[off] = *(const uint2*)t4;
                }
            }
        } else {
            // K -> row-major [m][c] (read once per block by attn), log2e-scaled
            float bb2[2][4];
#pragma unroll
            for (int ct = 0; ct < 2; ++ct)
#pragma unroll
                for (int r = 0; r < 4; ++r)
                    bb2[ct][r] = bk[c0 + ct * 16 + l4 * 4 + r] * LOG2E;
#pragma unroll
            for (int mt = 0; mt < 8; ++mt) {
                const int m = gm0 + mt * 16 + l15;
#pragma unroll
                for (int ct = 0; ct < 2; ++ct) {
                    _Float16 t4[4];
#pragma unroll
                    for (int r = 0; r < 4; ++r)
                        t4[r] = (_Float16)(acc[mt][ct][r] + bb2[ct][r]);
                    *(uint2*)&Kh[(size_t)m * D + c0 + ct * 16 + l4 * 4] =
                        *(const uint2*)t4;
                }
            }
        }
    }
}

// ---------------------------------------------------------------------------
// Flash attention v9 = v7 (fragment-layout register reads, launch_bounds
// (256,2) — the only verified-safe setting; (256,3+) spills) + software
// pipeline: V loads issued at iter start (consumed at PV ~400cy later),
// next-iter Q loads issued right after QK (consumed next iter), named
// double-buffer via unroll-by-2 (no runtime indexing). Running pointers
// (+8192 B/iter) replace per-load index math. Deferred rescale (THR=8).
// 512 blocks x 32 n-rows; 4 waves = 4 disjoint m-quarters (32 iters x 32 m).
// ---------------------------------------------------------------------------
#define VPP 40          // Ps row pitch (u16)
#define OBP 132         // Obuf row pitch (f32): 528 B, 16B-aligned

__global__ __launch_bounds__(256, 2) void attn_kernel(
    const u16* __restrict__ Kh, const u16* __restrict__ Qf,
    const u16* __restrict__ Vf, const float* __restrict__ Sc,
    float* __restrict__ out)
{
    __shared__ __align__(16) u16   Ps[4][2][16][VPP];   // 10 KB
    __shared__ __align__(16) float Obuf[2][32][OBP];    // 33.8 KB merge slots
    __shared__ float ml[4][2][32];                      // 1 KB

    const int tid = threadIdx.x;
    const int wv  = tid >> 6;          // m-quarter
    const int l   = tid & 63;
    const int l15 = l & 15;
    const int l4  = l >> 4;

    // XCD-affinity remap: each XCD pair serves one batch (K+Qf+Vf ~3 MB / L2)
    const int bx    = blockIdx.x;
    const int xcd   = bx & 7;
    const int batch = xcd >> 1;
    const int tile  = ((xcd & 1) << 6) | (bx >> 3);
    const int gr0   = batch * NPB + tile * 32;      // block's 32 K-rows (out rows)

    // ---- K A-frags (proven 16x16x32 mapping), held in registers all loop
    half8 kf[2][4];
#pragma unroll
    for (int nt = 0; nt < 2; ++nt)
#pragma unroll
        for (int kc = 0; kc < 4; ++kc)
            kf[nt][kc] = *(const half8*)(
                Kh + (size_t)(gr0 + nt * 16 + l15) * D + kc * 32 + l4 * 8);

    // ---- running fragment pointers (advance 4096 u16 = 8192 B per iter)
    const int  qtb = (batch * NPB + wv * 1024) >> 4;   // Q 16-m tile base
    const u16* qpA = Qf + ((size_t)qtb << 2) * 512 + l * 8;   // mt=0, kc*512 off
    const u16* qpB = qpA + 2048;                              // mt=1
    const int  vbb = wv * 32;
    const int  vl  = l15 * 4 + l4;                     // V lane permutation
    const u16* vpA = Vf + (size_t)batch * (D * NPB)
                     + ((size_t)vbb << 3) * 512 + vl * 8;     // ct 0..3
    const u16* vpB = vpA + 4 * 512;                           // ct 4..7

    f32x4 Oc[2][8];
#pragma unroll
    for (int nt = 0; nt < 2; ++nt)
#pragma unroll
        for (int ct = 0; ct < 8; ++ct)
            Oc[nt][ct] = (f32x4){0.f, 0.f, 0.f, 0.f};
    float mold[2][4], lsum[2][4];
#pragma unroll
    for (int nt = 0; nt < 2; ++nt)
#pragma unroll
        for (int r = 0; r < 4; ++r) { mold[nt][r] = -1e30f; lsum[nt][r] = 0.f; }

    // ---- prologue: Q fragments for it=0
    half8 qfA[2][4], qfB[2][4];
#pragma unroll
    for (int kc = 0; kc < 4; ++kc) {
        qfA[0][kc] = *(const half8*)(qpA + kc * 512);
        qfA[1][kc] = *(const half8*)(qpB + kc * 512);
    }

    // ---- one iteration; qfC = this iter's Q, qfN = loads next iter's Q
    auto body = [&](half8 (&qfC)[2][4], half8 (&qfN)[2][4]) {
        // 1. V loads for THIS iter (consumed at PV after softmax)
        half8 vf[8];
#pragma unroll
        for (int ct = 0; ct < 4; ++ct) {
            vf[ct]     = *(const half8*)(vpA + ct * 512);
            vf[4 + ct] = *(const half8*)(vpB + ct * 512);
        }
        vpA += 4096; vpB += 4096;

        // 2. S' = (K*log2e) @ Q^T : 32n x 32m, exp2 domain (proven path)
        f32x4 sacc[2][2];
        sacc[0][0] = (f32x4){0.f, 0.f, 0.f, 0.f};
        sacc[0][1] = (f32x4){0.f, 0.f, 0.f, 0.f};
        sacc[1][0] = (f32x4){0.f, 0.f, 0.f, 0.f};
        sacc[1][1] = (f32x4){0.f, 0.f, 0.f, 0.f};
        __builtin_amdgcn_s_setprio(1);
#pragma unroll
        for (int kc = 0; kc < 4; ++kc)
#pragma unroll
            for (int nt = 0; nt < 2; ++nt)
#pragma unroll
                for (int mt = 0; mt < 2; ++mt)
                    sacc[nt][mt] = __builtin_amdgcn_mfma_f32_16x16x32_f16(
                        kf[nt][kc], qfC[mt][kc], sacc[nt][mt], 0, 0, 0);
        __builtin_amdgcn_s_setprio(0);

        // 3. issue NEXT iter's Q loads (hide under softmax + PV)
        qpA += 4096; qpB += 4096;
#pragma unroll
        for (int kc = 0; kc < 4; ++kc) {
            qfN[0][kc] = *(const half8*)(qpA + kc * 512);
            qfN[1][kc] = *(const half8*)(qpB + kc * 512);
        }

        // 4. online softmax with deferred rescale (T13, THR=8; proven v8 logic)
        float rmax[2][4];
        int grow = 0;
#pragma unroll
        for (int nt = 0; nt < 2; ++nt)
#pragma unroll
            for (int r = 0; r < 4; ++r) {
                rmax[nt][r] = dpp_row_max(fmaxf(sacc[nt][0][r], sacc[nt][1][r]));
                grow |= (rmax[nt][r] > mold[nt][r] + THR) ? 1 : 0;
            }
        if (__any(grow)) {
#pragma unroll
            for (int nt = 0; nt < 2; ++nt)
#pragma unroll
                for (int r = 0; r < 4; ++r) {
                    const float mnew  = fmaxf(mold[nt][r], rmax[nt][r]);
                    const float alpha = EXP2(mold[nt][r] - mnew);
                    mold[nt][r] = mnew;
                    lsum[nt][r] *= alpha;
#pragma unroll
                    for (int ct = 0; ct < 8; ++ct) Oc[nt][ct][r] *= alpha;
                }
        }
#pragma unroll
        for (int nt = 0; nt < 2; ++nt)
#pragma unroll
            for (int r = 0; r < 4; ++r) {
                const float p0 = EXP2(sacc[nt][0][r] - mold[nt][r]);
                const float p1 = EXP2(sacc[nt][1][r] - mold[nt][r]);
                lsum[nt][r] += p0 + p1;
                Ps[wv][nt][l4 * 4 + r][l15]      = __builtin_bit_cast(u16, (_Float16)p0);
                Ps[wv][nt][l4 * 4 + r][16 + l15] = __builtin_bit_cast(u16, (_Float16)p1);
            }
        asm volatile("s_waitcnt lgkmcnt(0)" ::: "memory");   // wave-private Ps

        // 5. PV: O += P @ V (proven path)
        __builtin_amdgcn_s_setprio(1);
#pragma unroll
        for (int nt = 0; nt < 2; ++nt) {
            const half8 pf = *(const half8*)&Ps[wv][nt][l15][l4 * 8];
#pragma unroll
            for (int ct = 0; ct < 8; ++ct)
                Oc[nt][ct] = __builtin_amdgcn_mfma_f32_16x16x32_f16(
                    pf, vf[ct], Oc[nt][ct], 0, 0, 0);
        }
        __builtin_amdgcn_s_setprio(0);
    };

    for (int it2 = 0; it2 < 16; ++it2) {
        body(qfA, qfB);
        body(qfB, qfA);
    }
    // (last body's qf prefetch wraps into the adjacent workspace region —
    //  in-bounds reads, never consumed)

    // ---- full per-row sums across the 16 m-lanes (once, DPP)
#pragma unroll
    for (int nt = 0; nt < 2; ++nt)
#pragma unroll
        for (int r = 0; r < 4; ++r)
            lsum[nt][r] = dpp_row_sum(lsum[nt][r]);

    // ---- publish per-wave (m, l) per row
    if (l15 == 0) {
#pragma unroll
        for (int nt = 0; nt < 2; ++nt)
#pragma unroll
            for (int r = 0; r < 4; ++r) {
                ml[wv][0][nt * 16 + l4 * 4 + r] = mold[nt][r];
                ml[wv][1][nt * 16 + l4 * 4 + r] = lsum[nt][r];
            }
    }
    __syncthreads();

    // ---- scale factors into common max-frame
    float fw[2][4];
#pragma unroll
    for (int nt = 0; nt < 2; ++nt)
#pragma unroll
        for (int r = 0; r < 4; ++r) {
            const int row = nt * 16 + l4 * 4 + r;
            const float M = fmaxf(fmaxf(ml[0][0][row], ml[1][0][row]),
                                  fmaxf(ml[2][0][row], ml[3][0][row]));
            fw[nt][r] = EXP2(mold[nt][r] - M);
        }

    // ---- two-stage 4->2->1 additive merge (2 LDS slots)
    if (wv >= 2) {
#pragma unroll
        for (int nt = 0; nt < 2; ++nt)
#pragma unroll
            for (int r = 0; r < 4; ++r) {
                const int row = nt * 16 + l4 * 4 + r;
#pragma unroll
                for (int ct = 0; ct < 8; ++ct)
                    Obuf[wv - 2][row][ct * 16 + l15] = Oc[nt][ct][r] * fw[nt][r];
            }
    }
    __syncthreads();
    if (wv < 2) {
#pragma unroll
        for (int nt = 0; nt < 2; ++nt)
#pragma unroll
            for (int r = 0; r < 4; ++r) {
                const int row = nt * 16 + l4 * 4 + r;
#pragma unroll
                for (int ct = 0; ct < 8; ++ct)
                    Obuf[wv][row][ct * 16 + l15] += Oc[nt][ct][r] * fw[nt][r];
            }
    }
    __syncthreads();

    // ---- final: thread -> (row = wv*8 + l/8, 16 c per lane-octet)
    {
        const int row = wv * 8 + (l >> 3);
        const int cb  = (l & 7) * 16;
        const float M = fmaxf(fmaxf(ml[0][0][row], ml[1][0][row]),
                              fmaxf(ml[2][0][row], ml[3][0][row]));
        float L = 0.f;
#pragma unroll
        for (int s = 0; s < 4; ++s)
            L += ml[s][1][row] * EXP2(ml[s][0][row] - M);
        const float invL = 1.f / L;
        const size_t grow_ = (size_t)(gr0 + row);
#pragma unroll
        for (int j = 0; j < 4; ++j) {
            const int c = cb + j * 4;
            const f32x4 a = *(const f32x4*)&Obuf[0][row][c];
            const f32x4 b = *(const f32x4*)&Obuf[1][row][c];
            const float4 sc = *(const float4*)&Sc[grow_ * D + c];
            float4 o;
            o.x = (a[0] + b[0]) * invL + sc.x;
            o.y = (a[1] + b[1]) * invL + sc.y;
            o.z = (a[2] + b[2]) * invL + sc.z;
            o.w = (a[3] + b[3]) * invL + sc.w;
            *(float4*)&out[grow_ * D + c] = o;
        }
    }
}

extern "C" void kernel_launch(void* const* d_in, const int* in_sizes, int n_in,
                              void* d_out, int out_size, void* d_ws, size_t ws_size,
                              hipStream_t stream) {
    const float* x  = (const float*)d_in[0];
    const float* Wk = (const float*)d_in[1];
    const float* bk = (const float*)d_in[2];
    const float* Wq = (const float*)d_in[3];
    const float* bq = (const float*)d_in[4];
    const float* Wv = (const float*)d_in[5];
    const float* bv = (const float*)d_in[6];
    const float* Ws = (const float*)d_in[7];
    const float* bs = (const float*)d_in[8];
    float* out = (float*)d_out;

    u16*   Kh = (u16*)d_ws;                       // 4 MB fp16 [m][c] (log2e-scaled)
    u16*   Qf = Kh + (size_t)BN * D;              // 4 MB fp16, fragment layout
    u16*   Vf = Qf + (size_t)BN * D;              // 4 MB fp16, fragment layout
    float* Sc = (float*)(Vf + (size_t)BN * D);    // 8 MB fp32
    u16*   Wt = (u16*)(Sc + (size_t)BN * D);      // 256 KB fp16 W^T (4 mats)

    prep_kernel<<<128, 256, 0, stream>>>(Wk, Wq, Wv, Ws, Wt);
    proj_kernel<<<dim3(128, 4), 256, 0, stream>>>(x, Wt, bk, bq, bv, bs,
                                                  Kh, Qf, Vf, Sc);
    attn_kernel<<<512, 256, 0, stream>>>(Kh, Qf, Vf, Sc, out);
}